// Round 6
// baseline (13185.754 us; speedup 1.0000x reference)
//
#include <hip/hip_runtime.h>
#include <math.h>

#define NEG10K -10000.0f
// K=12 tags, START=10, STOP=11, B=64, T=1024, V=50000, D=256, Hh=256, 4Hh=1024

// ---------------- workspace layout (float offsets) ----------------
static const size_t OFF_WT_IH = 0;                  // [2][256][1024]  Wih^T per dir
static const size_t OFF_WT_HH = 524288;             // [2][256][1024]  Whh^T per dir
static const size_t OFF_BIAS  = 1048576;            // [2][1024]       bih+bhh
static const size_t OFF_WTAGD = 1050624;            // [2][16][256]    Wtag halves, k-padded to 16
static const size_t OFF_BTAG  = 1058816;            // [16]
static const size_t OFF_FEATS = 1058832;            // [2][64][1024][16] per-dir partial feats
static const size_t OFF_HC    = 3155984;            // [2][64][256] h carry between chunks
static const size_t OFF_CC    = 3188752;            // [2][64][256] c carry
static const size_t OFF_ZP    = 3221520;            // [32 grp][4 q][2 par][4 b][1024] partials
static const size_t OFF_CNT   = 4270096;            // [32 grp][256 steps] int counters
static const size_t OFF_G     = 4278288;            // [2][64][chunkT][1024] input projections

__device__ __forceinline__ float sigf(float x) { return 1.0f / (1.0f + expf(-x)); }

// ---------------- weight transposes: [1024][256] -> [256][1024] ----------------
__global__ __launch_bounds__(256) void k_transpose(
    const float* __restrict__ wih_f, const float* __restrict__ wih_b,
    const float* __restrict__ whh_f, const float* __restrict__ whh_b,
    float* __restrict__ ws) {
  __shared__ float tile[32][33];
  int z = blockIdx.z;
  const float* src = (z == 0) ? wih_f : (z == 1) ? wih_b : (z == 2) ? whh_f : whh_b;
  float* dst = ws + ((z < 2) ? (OFF_WT_IH + (size_t)z * 262144)
                             : (OFF_WT_HH + (size_t)(z - 2) * 262144));
  int r0 = blockIdx.y * 32;
  int c0 = blockIdx.x * 32;
  int tid = threadIdx.x;
  int c = tid & 31, rg = tid >> 5;
#pragma unroll
  for (int i = 0; i < 4; ++i) {
    int r = rg * 4 + i;
    tile[r][c] = src[(size_t)(r0 + r) * 256 + c0 + c];
  }
  __syncthreads();
  int r2 = tid & 31, cg = tid >> 5;
#pragma unroll
  for (int i = 0; i < 4; ++i) {
    int ccv = cg * 4 + i;
    dst[(size_t)(c0 + ccv) * 1024 + r0 + r2] = tile[r2][ccv];
  }
}

// ---------------- small prep ----------------
__global__ __launch_bounds__(256) void k_prep_small(
    const float* __restrict__ bih_f, const float* __restrict__ bhh_f,
    const float* __restrict__ bih_b, const float* __restrict__ bhh_b,
    const float* __restrict__ wtag, const float* __restrict__ btag,
    float* __restrict__ ws) {
  int i = blockIdx.x * 256 + threadIdx.x;
  if (i < 2048) {
    int d = i >> 10, n = i & 1023;
    ws[OFF_BIAS + i] = d ? (bih_b[n] + bhh_b[n]) : (bih_f[n] + bhh_f[n]);
  } else if (i < 2048 + 8192) {
    int r = i - 2048;
    int d = r >> 12, rem = r & 4095;
    int k = rem >> 8, j = rem & 255;
    ws[OFF_WTAGD + r] = (k < 12) ? wtag[(size_t)k * 512 + d * 256 + j] : 0.0f;
  } else if (i < 2048 + 8192 + 16) {
    int kk = i - 10240;
    ws[OFF_BTAG + kk] = (kk < 12) ? btag[kk] : 0.0f;
  }
}

// ---------------- G chunk = gather(emb, sentence) @ Wih^T + bias ----------------
__global__ __launch_bounds__(256) void k_gemm_g(
    const int* __restrict__ sentence, const float* __restrict__ emb,
    const float* __restrict__ ws_c, float* __restrict__ G,
    int t0, int cshift) {
  __shared__ float As[32][64];
  __shared__ float Bs[32][64];
  __shared__ int idx_s[64];
  int d = blockIdx.z;
  int m0 = blockIdx.y * 64, n0 = blockIdx.x * 64;
  int tid = threadIdx.x;
  int cmask = (1 << cshift) - 1;
  const float* Wt = ws_c + OFF_WT_IH + (size_t)d * 262144;
  if (tid < 64) {
    int m = m0 + tid;
    int b = m >> cshift, tt = m & cmask;
    int t = d ? (1023 - t0 - tt) : (t0 + tt);
    idx_s[tid] = sentence[(size_t)b * 1024 + t];
  }
  __syncthreads();
  float acc[4][4] = {};
  int tm = tid >> 4, tn = tid & 15;
  int am = tid & 63, ak = (tid >> 6) * 8;
  int bn = (tid & 15) * 4, bk = tid >> 4;
  for (int k0 = 0; k0 < 256; k0 += 32) {
    const float* ar = emb + (size_t)idx_s[am] * 256 + k0 + ak;
    float4 a0 = *(const float4*)ar;
    float4 a1 = *(const float4*)(ar + 4);
    float4 b0 = *(const float4*)(Wt + (size_t)(k0 + bk) * 1024 + n0 + bn);
    float4 b1 = *(const float4*)(Wt + (size_t)(k0 + bk + 16) * 1024 + n0 + bn);
    As[ak + 0][am] = a0.x; As[ak + 1][am] = a0.y; As[ak + 2][am] = a0.z; As[ak + 3][am] = a0.w;
    As[ak + 4][am] = a1.x; As[ak + 5][am] = a1.y; As[ak + 6][am] = a1.z; As[ak + 7][am] = a1.w;
    *(float4*)&Bs[bk][bn] = b0;
    *(float4*)&Bs[bk + 16][bn] = b1;
    __syncthreads();
#pragma unroll
    for (int kk = 0; kk < 32; ++kk) {
      float4 av = *(const float4*)&As[kk][tm * 4];
      float4 bv = *(const float4*)&Bs[kk][tn * 4];
      float avf[4] = {av.x, av.y, av.z, av.w};
      float bvf[4] = {bv.x, bv.y, bv.z, bv.w};
#pragma unroll
      for (int i = 0; i < 4; ++i)
#pragma unroll
        for (int j = 0; j < 4; ++j) acc[i][j] = fmaf(avf[i], bvf[j], acc[i][j]);
    }
    __syncthreads();
  }
  float4 bias = *(const float4*)(ws_c + OFF_BIAS + (size_t)d * 1024 + n0 + tn * 4);
#pragma unroll
  for (int i = 0; i < 4; ++i) {
    int m = m0 + tm * 4 + i;
    int b = m >> cshift, tt = m & cmask;
    float* gp = G + (((size_t)d * 64 + b) * (size_t)(cmask + 1) + tt) * 1024 + n0 + tn * 4;
    float4 v;
    v.x = acc[i][0] + bias.x; v.y = acc[i][1] + bias.y;
    v.z = acc[i][2] + bias.z; v.w = acc[i][3] + bias.w;
    *(float4*)gp = v;
  }
}

// ---------------- recurrent LSTM: 4-way k-split with cross-WG partial exchange ----
// 128 WGs = 32 groups x 4 k-quarters. Group = (dir, batch-quad of 4 batches).
// Each WG streams 256 KB/step (its k-quarter of Whh), publishes partial z via
// agent-scope stores, per-(group,step) counter barrier, then all 4 WGs read all
// partials and redundantly compute gates/h. One barrier per step.
#define FMA4(A, W, S) { A.x = fmaf(W.x, S, A.x); A.y = fmaf(W.y, S, A.y); \
                        A.z = fmaf(W.z, S, A.z); A.w = fmaf(W.w, S, A.w); }
__global__ __launch_bounds__(512, 4) void k_lstm_g(
    const float* __restrict__ ws_c, const float* __restrict__ G,
    const float* __restrict__ h0p, const float* __restrict__ c0p,
    const int* __restrict__ seq_lens, float* __restrict__ ws_mut,
    int t0, int chunkT, int first) {
  int bx = blockIdx.x;
  int g = bx >> 2, q = bx & 3;          // blocks of a (dir,q) land on same XCD (%8)
  int d = g & 1;
  int gb = (g >> 1) * 4;                // batch base (4 batches)
  const float* Wq = ws_c + OFF_WT_HH + (size_t)d * 262144 + (size_t)(q * 64) * 1024;
  float* zpg = ws_mut + OFF_ZP + (size_t)g * 32768;   // [4q][2par][4b][1024]
  int* cntg = (int*)(ws_mut + OFF_CNT) + g * 256;

  __shared__ float h_s[4][256];
  __shared__ float z_s[2][4][1024];     // [khalf][b][col]
  __shared__ float pfp_s[4][16][16];

  int tid = threadIdx.x;
  int kh = tid >> 8, cg = tid & 255, c4 = cg * 4;   // phase-A role
  int u = tid & 255, b2 = tid >> 8;                 // gate role: batches b2, b2+2
  int len0 = seq_lens[gb + b2], len1 = seq_lens[gb + b2 + 2];

  // q0 tag-head weights in registers: thread = (bc=tid>>8, ks=(tid>>4)&15, jg=tid&15)
  int cks = (tid >> 4) & 15, cjv = tid & 15, bc = tid >> 8;
  float wtreg[16];
  if (q == 0) {
#pragma unroll
    for (int i = 0; i < 16; ++i)
      wtreg[i] = ws_c[OFF_WTAGD + (size_t)d * 4096 + (size_t)cks * 256 + cjv + 16 * i];
  }

  float cc0, cc1;
  {
    size_t i0 = ((size_t)d * 64 + gb + b2) * 256 + u;
    size_t i1 = ((size_t)d * 64 + gb + b2 + 2) * 256 + u;
    if (first) {
      h_s[b2][u] = h0p[i0];     cc0 = c0p[i0];
      h_s[b2 + 2][u] = h0p[i1]; cc1 = c0p[i1];
    } else {
      h_s[b2][u] = ws_c[OFF_HC + i0];     cc0 = ws_c[OFF_CC + i0];
      h_s[b2 + 2][u] = ws_c[OFF_HC + i1]; cc1 = ws_c[OFF_CC + i1];
    }
  }
  __syncthreads();

  float* featsD = ws_mut + OFF_FEATS + (size_t)d * 1048576;

  for (int s = 0; s < chunkT; ++s) {
    int sg = t0 + s;
    int t = d ? (1023 - sg) : sg;
    int par = s & 1;
    // ---- G prefetch for this step's gates (hidden under phase A) ----
    float gp0[4], gp1[4];
    {
      const float* Ga = G + (((size_t)d * 64 + gb + b2) * (size_t)chunkT + s) * 1024 + u;
      const float* Gbp = G + (((size_t)d * 64 + gb + b2 + 2) * (size_t)chunkT + s) * 1024 + u;
      gp0[0] = Ga[0]; gp0[1] = Ga[256]; gp0[2] = Ga[512]; gp0[3] = Ga[768];
      gp1[0] = Gbp[0]; gp1[1] = Gbp[256]; gp1[2] = Gbp[512]; gp1[3] = Gbp[768];
    }
    // ---- q0: tag-head partials for PREVIOUS step's h (stable in phase A) ----
    if (q == 0 && s > 0) {
      float p0 = 0.0f, p1 = 0.0f;
#pragma unroll
      for (int i = 0; i < 16; ++i) {
        p0 = fmaf(h_s[bc][cjv + 16 * i], wtreg[i], p0);
        p1 = fmaf(h_s[bc + 2][cjv + 16 * i], wtreg[i], p1);
      }
      pfp_s[bc][cks][cjv] = p0;
      pfp_s[bc + 2][cks][cjv] = p1;
    }
    // ---- phase A: my k-quarter partial z, 4 cols x 4 batches ----
    float4 a0 = {0,0,0,0}, a1 = {0,0,0,0}, a2 = {0,0,0,0}, a3 = {0,0,0,0};
#pragma unroll 2
    for (int j4 = 0; j4 < 8; ++j4) {
      int k0 = kh * 32 + j4 * 4;
      float4 hv0 = *(const float4*)&h_s[0][k0];
      float4 hv1 = *(const float4*)&h_s[1][k0];
      float4 hv2 = *(const float4*)&h_s[2][k0];
      float4 hv3 = *(const float4*)&h_s[3][k0];
      const float* hp0 = (const float*)&hv0; const float* hp1 = (const float*)&hv1;
      const float* hp2 = (const float*)&hv2; const float* hp3 = (const float*)&hv3;
#pragma unroll
      for (int jj = 0; jj < 4; ++jj) {
        float4 w = *(const float4*)(Wq + (size_t)(k0 + jj) * 1024 + c4);
        FMA4(a0, w, hp0[jj]); FMA4(a1, w, hp1[jj]);
        FMA4(a2, w, hp2[jj]); FMA4(a3, w, hp3[jj]);
      }
    }
    *(float4*)&z_s[kh][0][c4] = a0;
    *(float4*)&z_s[kh][1][c4] = a1;
    *(float4*)&z_s[kh][2][c4] = a2;
    *(float4*)&z_s[kh][3][c4] = a3;
    __syncthreads();  // S1
    // ---- publish my quarter's partial (sum of 2 k-halves), agent-scope ----
#pragma unroll
    for (int e = 0; e < 2; ++e) {
      int f4 = tid * 2 + e;
      int b = f4 >> 8, col = (f4 & 255) * 4;
      float4 v0 = *(const float4*)&z_s[0][b][col];
      float4 v1 = *(const float4*)&z_s[1][b][col];
      float* dst = zpg + (((size_t)q * 2 + par) * 4 + b) * 1024 + col;
      __hip_atomic_store(dst + 0, v0.x + v1.x, __ATOMIC_RELAXED, __HIP_MEMORY_SCOPE_AGENT);
      __hip_atomic_store(dst + 1, v0.y + v1.y, __ATOMIC_RELAXED, __HIP_MEMORY_SCOPE_AGENT);
      __hip_atomic_store(dst + 2, v0.z + v1.z, __ATOMIC_RELAXED, __HIP_MEMORY_SCOPE_AGENT);
      __hip_atomic_store(dst + 3, v0.w + v1.w, __ATOMIC_RELAXED, __HIP_MEMORY_SCOPE_AGENT);
    }
    // ---- q0: reduce + store prev step's feats (pfp_s written before S1) ----
    if (q == 0 && s > 0 && tid < 64) {
      int fb = tid >> 4, kk = tid & 15;
      float sum = 0.0f;
#pragma unroll
      for (int i = 0; i < 16; ++i) sum += pfp_s[fb][kk][i];
      int tp = d ? (1023 - (sg - 1)) : (sg - 1);
      featsD[(size_t)(gb + fb) * 16384 + (size_t)tp * 16 + kk] = sum;
    }
    // ---- group barrier: arrive + spin (counter in device-coherent memory) ----
    if (tid == 0) {
      __hip_atomic_fetch_add(&cntg[s], 1, __ATOMIC_RELEASE, __HIP_MEMORY_SCOPE_AGENT);
      int it = 0;
      while (__hip_atomic_load(&cntg[s], __ATOMIC_ACQUIRE, __HIP_MEMORY_SCOPE_AGENT) < 4
             && it < 100000000) { ++it; __builtin_amdgcn_s_sleep(1); }
    }
    __syncthreads();  // S2
    // ---- gates: read all 4 quarters' partials, redundant everywhere ----
    {
      float z0[4];
#pragma unroll
      for (int gate = 0; gate < 4; ++gate) {
        float zz = gp0[gate];
#pragma unroll
        for (int qq = 0; qq < 4; ++qq)
          zz += __hip_atomic_load(zpg + (((size_t)qq * 2 + par) * 4 + b2) * 1024 + u + 256 * gate,
                                  __ATOMIC_RELAXED, __HIP_MEMORY_SCOPE_AGENT);
        z0[gate] = zz;
      }
      float cn = sigf(z0[1]) * cc0 + sigf(z0[0]) * tanhf(z0[2]);
      float hn = sigf(z0[3]) * tanhf(cn);
      bool m = t < len0;
      cc0 = m ? cn : cc0;
      h_s[b2][u] = m ? hn : h_s[b2][u];
    }
    {
      float z1[4];
#pragma unroll
      for (int gate = 0; gate < 4; ++gate) {
        float zz = gp1[gate];
#pragma unroll
        for (int qq = 0; qq < 4; ++qq)
          zz += __hip_atomic_load(zpg + (((size_t)qq * 2 + par) * 4 + b2 + 2) * 1024 + u + 256 * gate,
                                  __ATOMIC_RELAXED, __HIP_MEMORY_SCOPE_AGENT);
        z1[gate] = zz;
      }
      float cn = sigf(z1[1]) * cc1 + sigf(z1[0]) * tanhf(z1[2]);
      float hn = sigf(z1[3]) * tanhf(cn);
      bool m = t < len1;
      cc1 = m ? cn : cc1;
      h_s[b2 + 2][u] = m ? hn : h_s[b2 + 2][u];
    }
    __syncthreads();  // S3: h_s settled for next phase A
  }
  // ---- epilogue (q0): final step's tag-head + carries ----
  if (q == 0) {
    float p0 = 0.0f, p1 = 0.0f;
#pragma unroll
    for (int i = 0; i < 16; ++i) {
      p0 = fmaf(h_s[bc][cjv + 16 * i], wtreg[i], p0);
      p1 = fmaf(h_s[bc + 2][cjv + 16 * i], wtreg[i], p1);
    }
    pfp_s[bc][cks][cjv] = p0;
    pfp_s[bc + 2][cks][cjv] = p1;
    __syncthreads();
    if (tid < 64) {
      int fb = tid >> 4, kk = tid & 15;
      float sum = 0.0f;
#pragma unroll
      for (int i = 0; i < 16; ++i) sum += pfp_s[fb][kk][i];
      int sgl = t0 + chunkT - 1;
      int tl = d ? (1023 - sgl) : sgl;
      featsD[(size_t)(gb + fb) * 16384 + (size_t)tl * 16 + kk] = sum;
    }
    size_t i0 = ((size_t)d * 64 + gb + b2) * 256 + u;
    size_t i1 = ((size_t)d * 64 + gb + b2 + 2) * 256 + u;
    ws_mut[OFF_HC + i0] = h_s[b2][u];     ws_mut[OFF_CC + i0] = cc0;
    ws_mut[OFF_HC + i1] = h_s[b2 + 2][u]; ws_mut[OFF_CC + i1] = cc1;
  }
}

// ---------------- fallback fused LSTM (round-2, known-good) ----------------
__global__ __launch_bounds__(256) void k_lstm_fused(
    const float* __restrict__ ws_c, const int* __restrict__ sentence,
    const float* __restrict__ emb, const float* __restrict__ h0p,
    const float* __restrict__ c0p, const int* __restrict__ seq_lens,
    float* __restrict__ ws_mut) {
  int d = blockIdx.x & 1;
  int pr = blockIdx.x >> 1;
  int b0 = pr * 2, b1 = b0 + 1;
  const float* Wih = ws_c + OFF_WT_IH + (size_t)d * 262144;
  const float* Whh = ws_c + OFF_WT_HH + (size_t)d * 262144;
  __shared__ float h_s[2][256];
  __shared__ float x_s[2][2][256];
  __shared__ float z_s[2][1024];
  __shared__ int   sent_s[2][1024];
  __shared__ float wt_s[16][260];
  __shared__ float pfp_s[2][16][8];
  int tid = threadIdx.x;
  int len0 = seq_lens[b0], len1 = seq_lens[b1];
  for (int i = tid; i < 2048; i += 256)
    sent_s[i >> 10][i & 1023] = sentence[(size_t)(b0 + (i >> 10)) * 1024 + (i & 1023)];
  for (int i = tid; i < 4096; i += 256)
    wt_s[i >> 8][i & 255] = ws_c[OFF_WTAGD + (size_t)d * 4096 + i];
  h_s[0][tid] = h0p[((size_t)d * 64 + b0) * 256 + tid];
  h_s[1][tid] = h0p[((size_t)d * 64 + b1) * 256 + tid];
  float cc0 = c0p[((size_t)d * 64 + b0) * 256 + tid];
  float cc1 = c0p[((size_t)d * 64 + b1) * 256 + tid];
  int c4 = tid * 4;
  float4 bias_v = *(const float4*)(ws_c + OFF_BIAS + (size_t)d * 1024 + c4);
  __syncthreads();
  int t0 = d ? 1023 : 0;
  if (tid < 128) {
    int bb = tid >> 6, l = tid & 63;
    int row = sent_s[bb][t0];
    *(float4*)&x_s[0][bb][l * 4] = *(const float4*)(emb + (size_t)row * 256 + l * 4);
  }
  __syncthreads();
  float* featsD = ws_mut + OFF_FEATS + (size_t)d * 1048576;
  for (int s = 0; s < 1024; ++s) {
    int t = d ? (1023 - s) : s;
    int cur = s & 1, nxt = cur ^ 1;
    float4 pf = {0, 0, 0, 0};
    if (tid < 128) {
      int sn = (s < 1023) ? (s + 1) : 1023;
      int tn = d ? (1023 - sn) : sn;
      int bb = tid >> 6, l = tid & 63;
      pf = *(const float4*)(emb + (size_t)sent_s[bb][tn] * 256 + l * 4);
    }
    float4 a0 = bias_v, a1 = bias_v;
#pragma unroll 4
    for (int k = 0; k < 256; k += 4) {
      float4 xv0 = *(const float4*)&x_s[cur][0][k];
      float4 xv1 = *(const float4*)&x_s[cur][1][k];
      float4 hv0 = *(const float4*)&h_s[0][k];
      float4 hv1 = *(const float4*)&h_s[1][k];
      const float* wi = Wih + (size_t)k * 1024 + c4;
      const float* wh = Whh + (size_t)k * 1024 + c4;
      float4 wi0 = *(const float4*)(wi);
      float4 wi1 = *(const float4*)(wi + 1024);
      float4 wi2 = *(const float4*)(wi + 2048);
      float4 wi3 = *(const float4*)(wi + 3072);
      float4 wh0 = *(const float4*)(wh);
      float4 wh1 = *(const float4*)(wh + 1024);
      float4 wh2 = *(const float4*)(wh + 2048);
      float4 wh3 = *(const float4*)(wh + 3072);
      FMA4(a0, wi0, xv0.x); FMA4(a0, wi1, xv0.y); FMA4(a0, wi2, xv0.z); FMA4(a0, wi3, xv0.w);
      FMA4(a0, wh0, hv0.x); FMA4(a0, wh1, hv0.y); FMA4(a0, wh2, hv0.z); FMA4(a0, wh3, hv0.w);
      FMA4(a1, wi0, xv1.x); FMA4(a1, wi1, xv1.y); FMA4(a1, wi2, xv1.z); FMA4(a1, wi3, xv1.w);
      FMA4(a1, wh0, hv1.x); FMA4(a1, wh1, hv1.y); FMA4(a1, wh2, hv1.z); FMA4(a1, wh3, hv1.w);
    }
    *(float4*)&z_s[0][c4] = a0;
    *(float4*)&z_s[1][c4] = a1;
    __syncthreads();
    {
      float iv = z_s[0][tid], fv = z_s[0][tid + 256];
      float gv = z_s[0][tid + 512], ov = z_s[0][tid + 768];
      float cn = sigf(fv) * cc0 + sigf(iv) * tanhf(gv);
      float hn = sigf(ov) * tanhf(cn);
      bool m = t < len0;
      cc0 = m ? cn : cc0;
      h_s[0][tid] = m ? hn : h_s[0][tid];
    }
    {
      float iv = z_s[1][tid], fv = z_s[1][tid + 256];
      float gv = z_s[1][tid + 512], ov = z_s[1][tid + 768];
      float cn = sigf(fv) * cc1 + sigf(iv) * tanhf(gv);
      float hn = sigf(ov) * tanhf(cn);
      bool m = t < len1;
      cc1 = m ? cn : cc1;
      h_s[1][tid] = m ? hn : h_s[1][tid];
    }
    if (tid < 128) {
      int bb = tid >> 6, l = tid & 63;
      *(float4*)&x_s[nxt][bb][l * 4] = pf;
    }
    __syncthreads();
    {
      int b2 = tid >> 7, r = tid & 127;
      int ks = r >> 3, jg = r & 7;
      const float* hv = &h_s[b2][jg * 32];
      const float* wv = &wt_s[ks][jg * 32];
      float p = 0.0f;
#pragma unroll
      for (int i = 0; i < 32; ++i) p = fmaf(hv[i], wv[i], p);
      pfp_s[b2][ks][jg] = p;
    }
    __syncthreads();
    if (tid < 32) {
      int b = tid >> 4, k = tid & 15;
      float sum = 0.0f;
#pragma unroll
      for (int i = 0; i < 8; ++i) sum += pfp_s[b][k][i];
      featsD[(size_t)(b0 + b) * 16384 + (size_t)t * 16 + k] = sum;
    }
  }
}

// ---------------- Viterbi + backtrace, one wave per batch element ----------------
__global__ __launch_bounds__(64) void k_viterbi(const float* __restrict__ ws_c,
                                                const float* __restrict__ trans,
                                                const int* __restrict__ seq_lens,
                                                float* __restrict__ out) {
  __shared__ char bp_s[1024][12];
  int b = blockIdx.x, lane = threadIdx.x;
  int len = seq_lens[b];
  float trow[12];
#pragma unroll
  for (int p = 0; p < 12; ++p) trow[p] = (lane < 12) ? trans[lane * 12 + p] : 0.0f;
  float tb = (lane < 16) ? ws_c[OFF_BTAG + lane] : 0.0f;
  float fv = (lane == 10) ? 0.0f : NEG10K;  // START=10
  const float* ff = ws_c + OFF_FEATS + (size_t)b * 16384;
  const float* fb = ws_c + OFF_FEATS + 1048576 + (size_t)b * 16384;
  for (int t = 0; t < 1024; ++t) {
    float ft = (lane < 16) ? (ff[t * 16 + lane] + fb[t * 16 + lane] + tb) : 0.0f;
    float best = -3.0e38f; int arg = 0;
#pragma unroll
    for (int p = 0; p < 12; ++p) {
      float s = __shfl(fv, p) + trow[p];
      if (s > best) { best = s; arg = p; }
    }
    bool m = t < len;
    if (m) fv = best + ft;
    if (lane < 12) bp_s[t][lane] = (char)(m ? arg : lane);
  }
  float term = (lane < 12) ? fv + trans[132 + lane] : -3.0e38f;  // STOP row = 11
  float bestv = -3.0e38f; int bestp = 0;
#pragma unroll
  for (int p = 0; p < 12; ++p) {
    float v = __shfl(term, p);
    if (v > bestv) { bestv = v; bestp = p; }
  }
  __syncthreads();
  if (lane == 0) {
    out[b] = bestv;
    int tag = bestp;
    float* po = out + 64 + (size_t)b * 1024;
    for (int t = 1023; t >= 0; --t) {
      po[t] = (t < len) ? (float)tag : 0.0f;
      tag = bp_s[t][tag];
    }
  }
}

extern "C" void kernel_launch(void* const* d_in, const int* in_sizes, int n_in,
                              void* d_out, int out_size, void* d_ws, size_t ws_size,
                              hipStream_t stream) {
  (void)in_sizes; (void)n_in; (void)out_size;
  const int*   sentence = (const int*)d_in[0];
  const int*   seq_lens = (const int*)d_in[1];
  const float* emb      = (const float*)d_in[2];
  const float* wih_f    = (const float*)d_in[3];
  const float* whh_f    = (const float*)d_in[4];
  const float* bih_f    = (const float*)d_in[5];
  const float* bhh_f    = (const float*)d_in[6];
  const float* wih_b    = (const float*)d_in[7];
  const float* whh_b    = (const float*)d_in[8];
  const float* bih_b    = (const float*)d_in[9];
  const float* bhh_b    = (const float*)d_in[10];
  const float* wtag     = (const float*)d_in[11];
  const float* btag     = (const float*)d_in[12];
  const float* trans    = (const float*)d_in[13];
  const float* h0p      = (const float*)d_in[14];
  const float* c0p      = (const float*)d_in[15];
  float* ws  = (float*)d_ws;
  float* out = (float*)d_out;
  size_t avail = ws_size / 4;
  if (avail < OFF_FEATS + 2097152) return;

  int chunkT = 0;
  const int opts[4] = {256, 128, 64, 32};
  for (int i = 0; i < 4; ++i)
    if (OFF_G + (size_t)131072 * opts[i] <= avail) { chunkT = opts[i]; break; }

  k_transpose<<<dim3(8, 32, 4), 256, 0, stream>>>(wih_f, wih_b, whh_f, whh_b, ws);
  k_prep_small<<<41, 256, 0, stream>>>(bih_f, bhh_f, bih_b, bhh_b, wtag, btag, ws);
  if (chunkT) {
    int cshift = 31 - __builtin_clz(chunkT);
    int nc = 1024 / chunkT;
    for (int c = 0; c < nc; ++c) {
      int t0 = c * chunkT;
      k_gemm_g<<<dim3(16, chunkT, 2), 256, 0, stream>>>(sentence, emb, ws, ws + OFF_G,
                                                        t0, cshift);
      hipMemsetAsync((char*)d_ws + OFF_CNT * 4, 0, 32 * 256 * 4, stream);
      k_lstm_g<<<128, 512, 0, stream>>>(ws, ws + OFF_G, h0p, c0p, seq_lens, ws,
                                        t0, chunkT, c == 0);
    }
  } else {
    k_lstm_fused<<<64, 256, 0, stream>>>(ws, sentence, emb, h0p, c0p, seq_lens, ws);
  }
  k_viterbi<<<64, 64, 0, stream>>>(ws, trans, seq_lens, out);
}

// Round 7
// 11491.750 us; speedup vs baseline: 1.1474x; 1.1474x over previous
//
#include <hip/hip_runtime.h>
#include <math.h>

#define NEG10K -10000.0f
// K=12 tags, START=10, STOP=11, B=64, T=1024, V=50000, D=256, Hh=256, 4Hh=1024

// ---------------- workspace layout (float offsets) ----------------
static const size_t OFF_WT_IH = 0;                  // [2][256][1024]  Wih^T per dir
static const size_t OFF_WT_HH = 524288;             // [2][256][1024]  Whh^T per dir
static const size_t OFF_BIAS  = 1048576;            // [2][1024]       bih+bhh
static const size_t OFF_WTAGD = 1050624;            // [2][16][256]    Wtag halves, k-padded to 16
static const size_t OFF_BTAG  = 1058816;            // [16]
static const size_t OFF_FEATS = 1058832;            // [2][64][1024][16] per-dir partial feats
static const size_t OFF_HC    = 3155984;            // [2][64][256] h carry between chunks
static const size_t OFF_CC    = 3188752;            // [2][64][256] c carry
static const size_t OFF_HPUB  = 3221520;            // [16 grp][2 par][4 q][8 b][64] h slices
static const size_t OFF_CNT   = 3287056;            // [16 grp][256 steps] int counters
static const size_t OFF_G     = 3291152;            // [2][64][chunkT][1024] input projections

__device__ __forceinline__ float sigf(float x) { return 1.0f / (1.0f + expf(-x)); }

// ---------------- weight transposes: [1024][256] -> [256][1024] ----------------
__global__ __launch_bounds__(256) void k_transpose(
    const float* __restrict__ wih_f, const float* __restrict__ wih_b,
    const float* __restrict__ whh_f, const float* __restrict__ whh_b,
    float* __restrict__ ws) {
  __shared__ float tile[32][33];
  int z = blockIdx.z;
  const float* src = (z == 0) ? wih_f : (z == 1) ? wih_b : (z == 2) ? whh_f : whh_b;
  float* dst = ws + ((z < 2) ? (OFF_WT_IH + (size_t)z * 262144)
                             : (OFF_WT_HH + (size_t)(z - 2) * 262144));
  int r0 = blockIdx.y * 32;
  int c0 = blockIdx.x * 32;
  int tid = threadIdx.x;
  int c = tid & 31, rg = tid >> 5;
#pragma unroll
  for (int i = 0; i < 4; ++i) {
    int r = rg * 4 + i;
    tile[r][c] = src[(size_t)(r0 + r) * 256 + c0 + c];
  }
  __syncthreads();
  int r2 = tid & 31, cg = tid >> 5;
#pragma unroll
  for (int i = 0; i < 4; ++i) {
    int ccv = cg * 4 + i;
    dst[(size_t)(c0 + ccv) * 1024 + r0 + r2] = tile[r2][ccv];
  }
}

// ---------------- small prep ----------------
__global__ __launch_bounds__(256) void k_prep_small(
    const float* __restrict__ bih_f, const float* __restrict__ bhh_f,
    const float* __restrict__ bih_b, const float* __restrict__ bhh_b,
    const float* __restrict__ wtag, const float* __restrict__ btag,
    float* __restrict__ ws) {
  int i = blockIdx.x * 256 + threadIdx.x;
  if (i < 2048) {
    int d = i >> 10, n = i & 1023;
    ws[OFF_BIAS + i] = d ? (bih_b[n] + bhh_b[n]) : (bih_f[n] + bhh_f[n]);
  } else if (i < 2048 + 8192) {
    int r = i - 2048;
    int d = r >> 12, rem = r & 4095;
    int k = rem >> 8, j = rem & 255;
    ws[OFF_WTAGD + r] = (k < 12) ? wtag[(size_t)k * 512 + d * 256 + j] : 0.0f;
  } else if (i < 2048 + 8192 + 16) {
    int kk = i - 10240;
    ws[OFF_BTAG + kk] = (kk < 12) ? btag[kk] : 0.0f;
  }
}

// ---------------- G chunk = gather(emb, sentence) @ Wih^T + bias ----------------
__global__ __launch_bounds__(256) void k_gemm_g(
    const int* __restrict__ sentence, const float* __restrict__ emb,
    const float* __restrict__ ws_c, float* __restrict__ G,
    int t0, int cshift) {
  __shared__ float As[32][64];
  __shared__ float Bs[32][64];
  __shared__ int idx_s[64];
  int d = blockIdx.z;
  int m0 = blockIdx.y * 64, n0 = blockIdx.x * 64;
  int tid = threadIdx.x;
  int cmask = (1 << cshift) - 1;
  const float* Wt = ws_c + OFF_WT_IH + (size_t)d * 262144;
  if (tid < 64) {
    int m = m0 + tid;
    int b = m >> cshift, tt = m & cmask;
    int t = d ? (1023 - t0 - tt) : (t0 + tt);
    idx_s[tid] = sentence[(size_t)b * 1024 + t];
  }
  __syncthreads();
  float acc[4][4] = {};
  int tm = tid >> 4, tn = tid & 15;
  int am = tid & 63, ak = (tid >> 6) * 8;
  int bn = (tid & 15) * 4, bk = tid >> 4;
  for (int k0 = 0; k0 < 256; k0 += 32) {
    const float* ar = emb + (size_t)idx_s[am] * 256 + k0 + ak;
    float4 a0 = *(const float4*)ar;
    float4 a1 = *(const float4*)(ar + 4);
    float4 b0 = *(const float4*)(Wt + (size_t)(k0 + bk) * 1024 + n0 + bn);
    float4 b1 = *(const float4*)(Wt + (size_t)(k0 + bk + 16) * 1024 + n0 + bn);
    As[ak + 0][am] = a0.x; As[ak + 1][am] = a0.y; As[ak + 2][am] = a0.z; As[ak + 3][am] = a0.w;
    As[ak + 4][am] = a1.x; As[ak + 5][am] = a1.y; As[ak + 6][am] = a1.z; As[ak + 7][am] = a1.w;
    *(float4*)&Bs[bk][bn] = b0;
    *(float4*)&Bs[bk + 16][bn] = b1;
    __syncthreads();
#pragma unroll
    for (int kk = 0; kk < 32; ++kk) {
      float4 av = *(const float4*)&As[kk][tm * 4];
      float4 bv = *(const float4*)&Bs[kk][tn * 4];
      float avf[4] = {av.x, av.y, av.z, av.w};
      float bvf[4] = {bv.x, bv.y, bv.z, bv.w};
#pragma unroll
      for (int i = 0; i < 4; ++i)
#pragma unroll
        for (int j = 0; j < 4; ++j) acc[i][j] = fmaf(avf[i], bvf[j], acc[i][j]);
    }
    __syncthreads();
  }
  float4 bias = *(const float4*)(ws_c + OFF_BIAS + (size_t)d * 1024 + n0 + tn * 4);
#pragma unroll
  for (int i = 0; i < 4; ++i) {
    int m = m0 + tm * 4 + i;
    int b = m >> cshift, tt = m & cmask;
    float* gp = G + (((size_t)d * 64 + b) * (size_t)(cmask + 1) + tt) * 1024 + n0 + tn * 4;
    float4 v;
    v.x = acc[i][0] + bias.x; v.y = acc[i][1] + bias.y;
    v.z = acc[i][2] + bias.z; v.w = acc[i][3] + bias.w;
    *(float4*)gp = v;
  }
}

// ---------------- recurrent LSTM: column-split (hidden-unit split) ----------------
// 64 WGs = 16 groups (2 dirs x 8 batch-octets) x 4 unit-quarters.
// WG (g,q) owns hidden units [64q,64q+64): streams W slice [256 k][its 256 gate
// cols] = 256 KB/step, computes its z cols FULLY (no partial exchange), applies
// gates locally, publishes only its h-slice (2 KB) via device-coherent stores.
#define FMA4(A, W, S) { A.x = fmaf(W.x, S, A.x); A.y = fmaf(W.y, S, A.y); \
                        A.z = fmaf(W.z, S, A.z); A.w = fmaf(W.w, S, A.w); }
__global__ __launch_bounds__(512, 2) void k_lstm_g(
    const float* __restrict__ ws_c, const float* __restrict__ G,
    const float* __restrict__ h0p, const float* __restrict__ c0p,
    const int* __restrict__ seq_lens, float* __restrict__ ws_mut,
    int t0, int chunkT, int first) {
  int bx = blockIdx.x;
  int q = bx >> 4, og = (bx >> 1) & 7, d = bx & 1;  // same-XCD colocation heuristic
  int g = og * 2 + d;
  int gb = og * 8;                                   // 8 batches per group
  const float* Whh = ws_c + OFF_WT_HH + (size_t)d * 262144;  // [256][1024]
  float* hpub = ws_mut + OFF_HPUB;
  int* cntg = (int*)(ws_mut + OFF_CNT) + g * 256;

  __shared__ float h_full[8][256];       // 8 KB
  __shared__ float zp[4][8][256];        // 32 KB (2-stage kw reduction)
  __shared__ float pfp[8][16][32];       // 16 KB (q0 tag-head partials)

  int tid = threadIdx.x;
  int kw = tid >> 6, cw = tid & 63;      // GEMV role: wave kw, lane cw
  int b = tid >> 6, ul = tid & 63;       // gates role: batch b, own-unit ul
  int gate = cw >> 4, ul4 = (cw & 15) * 4;
  int wcol = gate * 256 + q * 64 + ul4;  // col offset in Wt_hh row
  int mylen = seq_lens[gb + b];

  // q0 tag-head weights in registers: thread = (ks=(tid>>5)&15, jg=tid&31)
  int ks = (tid >> 5) & 15, jg = tid & 31;
  float wtreg[8];
  if (q == 0) {
#pragma unroll
    for (int i = 0; i < 8; ++i)
      wtreg[i] = ws_c[OFF_WTAGD + (size_t)d * 4096 + (size_t)ks * 256 + jg + 32 * i];
  }

  // prologue: full h + own c slice from carry
  {
    const float* hs = first ? h0p : (ws_c + OFF_HC);
#pragma unroll
    for (int e = 0; e < 4; ++e) {
      int i = e * 512 + tid;
      int bb = i >> 8, uu = i & 255;
      h_full[bb][uu] = hs[((size_t)d * 64 + gb + bb) * 256 + uu];
    }
  }
  float cc;
  {
    const float* cs = first ? c0p : (ws_c + OFF_CC);
    cc = cs[((size_t)d * 64 + gb + b) * 256 + q * 64 + ul];
  }
  __syncthreads();

  float* featsD = ws_mut + OFF_FEATS + (size_t)d * 1048576;

  for (int s = 0; s < chunkT; ++s) {
    int sg = t0 + s;
    int t = d ? (1023 - sg) : sg;
    // ---- exchange: wait for step s-1's h publishes, rebuild h_full ----
    if (s > 0) {
      if (tid == 0) {
        long it = 0;
        while (__hip_atomic_load(&cntg[s - 1], __ATOMIC_ACQUIRE,
                                 __HIP_MEMORY_SCOPE_AGENT) < 4 &&
               it < 400000000L) { ++it; __builtin_amdgcn_s_sleep(4); }
      }
      __syncthreads();
      int parp = (s - 1) & 1;
      const float* hp = hpub + ((size_t)(g * 2 + parp)) * 2048;
#pragma unroll
      for (int e = 0; e < 4; ++e) {
        int i = e * 512 + tid;
        int qp = i >> 9, j = i & 511;
        float v = __hip_atomic_load(hp + (size_t)qp * 512 + j, __ATOMIC_RELAXED,
                                    __HIP_MEMORY_SCOPE_AGENT);
        h_full[j >> 6][qp * 64 + (j & 63)] = v;
      }
      __syncthreads();
    }
    // ---- G prefetch for this step (consumed in gates phase) ----
    float gpf[4];
    {
      const float* Gr = G + (((size_t)d * 64 + gb + b) * (size_t)chunkT + s) * 1024
                        + q * 64 + ul;
#pragma unroll
      for (int g4 = 0; g4 < 4; ++g4) gpf[g4] = Gr[g4 * 256];
    }
    // ---- q0: tag-head partials for token s-1 (h_full = post-token-(s-1)) ----
    if (q == 0 && s > 0) {
#pragma unroll
      for (int b8 = 0; b8 < 8; ++b8) {
        float p = 0.0f;
#pragma unroll
        for (int i = 0; i < 8; ++i)
          p = fmaf(h_full[b8][jg + 32 * i], wtreg[i], p);
        pfp[b8][ks][jg] = p;
      }
    }
    // ---- GEMV: my k-slice (32 rows) x my 4 cols x 8 batches ----
    float4 acc[8] = {};
    const float* Wb = Whh + wcol;
#pragma unroll
    for (int j4 = 0; j4 < 8; ++j4) {
      int k0 = kw * 32 + j4 * 4;
      float4 hv[8];
#pragma unroll
      for (int b8 = 0; b8 < 8; ++b8) hv[b8] = *(const float4*)&h_full[b8][k0];
      const float* hp = (const float*)hv;
#pragma unroll
      for (int jj = 0; jj < 4; ++jj) {
        float4 w = *(const float4*)(Wb + (size_t)(k0 + jj) * 1024);
#pragma unroll
        for (int b8 = 0; b8 < 8; ++b8) FMA4(acc[b8], w, hp[b8 * 4 + jj]);
      }
    }
    // ---- 2-stage kw reduction (8 -> 4 in regs, 4 -> 1 in gates read) ----
    if (kw >= 4) {
#pragma unroll
      for (int b8 = 0; b8 < 8; ++b8) *(float4*)&zp[kw - 4][b8][cw * 4] = acc[b8];
    }
    __syncthreads();
    if (kw < 4) {
#pragma unroll
      for (int b8 = 0; b8 < 8; ++b8) {
        float4 o = *(const float4*)&zp[kw][b8][cw * 4];
        o.x += acc[b8].x; o.y += acc[b8].y; o.z += acc[b8].z; o.w += acc[b8].w;
        *(float4*)&zp[kw][b8][cw * 4] = o;
      }
    }
    __syncthreads();
    // ---- gates for (batch b, own unit ul) ----
    float hw;
    {
      float z[4];
#pragma unroll
      for (int g4 = 0; g4 < 4; ++g4) {
        int c = g4 * 64 + ul;
        z[g4] = gpf[g4] + zp[0][b][c] + zp[1][b][c] + zp[2][b][c] + zp[3][b][c];
      }
      float cn = sigf(z[1]) * cc + sigf(z[0]) * tanhf(z[2]);
      float hn = sigf(z[3]) * tanhf(cn);
      bool m = t < mylen;
      cc = m ? cn : cc;
      float hold = h_full[b][q * 64 + ul];
      hw = m ? hn : hold;
      h_full[b][q * 64 + ul] = hw;
    }
    // ---- q0: reduce + store feats for token s-1 ----
    if (q == 0 && s > 0 && tid < 128) {
      int fb = tid >> 4, kk = tid & 15;
      float sum = 0.0f;
#pragma unroll
      for (int i = 0; i < 32; ++i) sum += pfp[fb][kk][i];
      int tp = d ? (1023 - (sg - 1)) : (sg - 1);
      featsD[(size_t)(gb + fb) * 16384 + (size_t)tp * 16 + kk] = sum;
    }
    // ---- publish own h-slice, drain, then release-add counter ----
    {
      int par = s & 1;
      __hip_atomic_store(hpub + ((size_t)(g * 2 + par) * 4 + q) * 512 + b * 64 + ul,
                         hw, __ATOMIC_RELAXED, __HIP_MEMORY_SCOPE_AGENT);
    }
    __syncthreads();  // drains all lanes' publish stores (vmcnt0 before barrier)
    if (tid == 0)
      __hip_atomic_fetch_add(&cntg[s], 1, __ATOMIC_RELEASE, __HIP_MEMORY_SCOPE_AGENT);
  }
  // ---- epilogue: final exchange + last token's tag-head + carries ----
  if (tid == 0) {
    long it = 0;
    while (__hip_atomic_load(&cntg[chunkT - 1], __ATOMIC_ACQUIRE,
                             __HIP_MEMORY_SCOPE_AGENT) < 4 &&
           it < 400000000L) { ++it; __builtin_amdgcn_s_sleep(4); }
  }
  __syncthreads();
  {
    int parp = (chunkT - 1) & 1;
    const float* hp = hpub + ((size_t)(g * 2 + parp)) * 2048;
#pragma unroll
    for (int e = 0; e < 4; ++e) {
      int i = e * 512 + tid;
      int qp = i >> 9, j = i & 511;
      float v = __hip_atomic_load(hp + (size_t)qp * 512 + j, __ATOMIC_RELAXED,
                                  __HIP_MEMORY_SCOPE_AGENT);
      h_full[j >> 6][qp * 64 + (j & 63)] = v;
    }
  }
  __syncthreads();
  if (q == 0) {
#pragma unroll
    for (int b8 = 0; b8 < 8; ++b8) {
      float p = 0.0f;
#pragma unroll
      for (int i = 0; i < 8; ++i) p = fmaf(h_full[b8][jg + 32 * i], wtreg[i], p);
      pfp[b8][ks][jg] = p;
    }
  }
  __syncthreads();
  if (q == 0 && tid < 128) {
    int fb = tid >> 4, kk = tid & 15;
    float sum = 0.0f;
#pragma unroll
    for (int i = 0; i < 32; ++i) sum += pfp[fb][kk][i];
    int sgl = t0 + chunkT - 1;
    int tl = d ? (1023 - sgl) : sgl;
    featsD[(size_t)(gb + fb) * 16384 + (size_t)tl * 16 + kk] = sum;
  }
  {
    size_t ci = ((size_t)d * 64 + gb + b) * 256 + q * 64 + ul;
    ws_mut[OFF_HC + ci] = h_full[b][q * 64 + ul];
    ws_mut[OFF_CC + ci] = cc;
  }
}

// ---------------- fallback fused LSTM (round-2, known-good) ----------------
__global__ __launch_bounds__(256) void k_lstm_fused(
    const float* __restrict__ ws_c, const int* __restrict__ sentence,
    const float* __restrict__ emb, const float* __restrict__ h0p,
    const float* __restrict__ c0p, const int* __restrict__ seq_lens,
    float* __restrict__ ws_mut) {
  int d = blockIdx.x & 1;
  int pr = blockIdx.x >> 1;
  int b0 = pr * 2, b1 = b0 + 1;
  const float* Wih = ws_c + OFF_WT_IH + (size_t)d * 262144;
  const float* Whh = ws_c + OFF_WT_HH + (size_t)d * 262144;
  __shared__ float h_s[2][256];
  __shared__ float x_s[2][2][256];
  __shared__ float z_s[2][1024];
  __shared__ int   sent_s[2][1024];
  __shared__ float wt_s[16][260];
  __shared__ float pfp_s[2][16][8];
  int tid = threadIdx.x;
  int len0 = seq_lens[b0], len1 = seq_lens[b1];
  for (int i = tid; i < 2048; i += 256)
    sent_s[i >> 10][i & 1023] = sentence[(size_t)(b0 + (i >> 10)) * 1024 + (i & 1023)];
  for (int i = tid; i < 4096; i += 256)
    wt_s[i >> 8][i & 255] = ws_c[OFF_WTAGD + (size_t)d * 4096 + i];
  h_s[0][tid] = h0p[((size_t)d * 64 + b0) * 256 + tid];
  h_s[1][tid] = h0p[((size_t)d * 64 + b1) * 256 + tid];
  float cc0 = c0p[((size_t)d * 64 + b0) * 256 + tid];
  float cc1 = c0p[((size_t)d * 64 + b1) * 256 + tid];
  int c4 = tid * 4;
  float4 bias_v = *(const float4*)(ws_c + OFF_BIAS + (size_t)d * 1024 + c4);
  __syncthreads();
  int t0 = d ? 1023 : 0;
  if (tid < 128) {
    int bb = tid >> 6, l = tid & 63;
    int row = sent_s[bb][t0];
    *(float4*)&x_s[0][bb][l * 4] = *(const float4*)(emb + (size_t)row * 256 + l * 4);
  }
  __syncthreads();
  float* featsD = ws_mut + OFF_FEATS + (size_t)d * 1048576;
  for (int s = 0; s < 1024; ++s) {
    int t = d ? (1023 - s) : s;
    int cur = s & 1, nxt = cur ^ 1;
    float4 pf = {0, 0, 0, 0};
    if (tid < 128) {
      int sn = (s < 1023) ? (s + 1) : 1023;
      int tn = d ? (1023 - sn) : sn;
      int bb = tid >> 6, l = tid & 63;
      pf = *(const float4*)(emb + (size_t)sent_s[bb][tn] * 256 + l * 4);
    }
    float4 a0 = bias_v, a1 = bias_v;
#pragma unroll 4
    for (int k = 0; k < 256; k += 4) {
      float4 xv0 = *(const float4*)&x_s[cur][0][k];
      float4 xv1 = *(const float4*)&x_s[cur][1][k];
      float4 hv0 = *(const float4*)&h_s[0][k];
      float4 hv1 = *(const float4*)&h_s[1][k];
      const float* wi = Wih + (size_t)k * 1024 + c4;
      const float* wh = Whh + (size_t)k * 1024 + c4;
      float4 wi0 = *(const float4*)(wi);
      float4 wi1 = *(const float4*)(wi + 1024);
      float4 wi2 = *(const float4*)(wi + 2048);
      float4 wi3 = *(const float4*)(wi + 3072);
      float4 wh0 = *(const float4*)(wh);
      float4 wh1 = *(const float4*)(wh + 1024);
      float4 wh2 = *(const float4*)(wh + 2048);
      float4 wh3 = *(const float4*)(wh + 3072);
      FMA4(a0, wi0, xv0.x); FMA4(a0, wi1, xv0.y); FMA4(a0, wi2, xv0.z); FMA4(a0, wi3, xv0.w);
      FMA4(a0, wh0, hv0.x); FMA4(a0, wh1, hv0.y); FMA4(a0, wh2, hv0.z); FMA4(a0, wh3, hv0.w);
      FMA4(a1, wi0, xv1.x); FMA4(a1, wi1, xv1.y); FMA4(a1, wi2, xv1.z); FMA4(a1, wi3, xv1.w);
      FMA4(a1, wh0, hv1.x); FMA4(a1, wh1, hv1.y); FMA4(a1, wh2, hv1.z); FMA4(a1, wh3, hv1.w);
    }
    *(float4*)&z_s[0][c4] = a0;
    *(float4*)&z_s[1][c4] = a1;
    __syncthreads();
    {
      float iv = z_s[0][tid], fv = z_s[0][tid + 256];
      float gv = z_s[0][tid + 512], ov = z_s[0][tid + 768];
      float cn = sigf(fv) * cc0 + sigf(iv) * tanhf(gv);
      float hn = sigf(ov) * tanhf(cn);
      bool m = t < len0;
      cc0 = m ? cn : cc0;
      h_s[0][tid] = m ? hn : h_s[0][tid];
    }
    {
      float iv = z_s[1][tid], fv = z_s[1][tid + 256];
      float gv = z_s[1][tid + 512], ov = z_s[1][tid + 768];
      float cn = sigf(fv) * cc1 + sigf(iv) * tanhf(gv);
      float hn = sigf(ov) * tanhf(cn);
      bool m = t < len1;
      cc1 = m ? cn : cc1;
      h_s[1][tid] = m ? hn : h_s[1][tid];
    }
    if (tid < 128) {
      int bb = tid >> 6, l = tid & 63;
      *(float4*)&x_s[nxt][bb][l * 4] = pf;
    }
    __syncthreads();
    {
      int b2 = tid >> 7, r = tid & 127;
      int ks = r >> 3, jg = r & 7;
      const float* hv = &h_s[b2][jg * 32];
      const float* wv = &wt_s[ks][jg * 32];
      float p = 0.0f;
#pragma unroll
      for (int i = 0; i < 32; ++i) p = fmaf(hv[i], wv[i], p);
      pfp_s[b2][ks][jg] = p;
    }
    __syncthreads();
    if (tid < 32) {
      int b = tid >> 4, k = tid & 15;
      float sum = 0.0f;
#pragma unroll
      for (int i = 0; i < 8; ++i) sum += pfp_s[b][k][i];
      featsD[(size_t)(b0 + b) * 16384 + (size_t)t * 16 + k] = sum;
    }
  }
}

// ---------------- Viterbi + backtrace, one wave per batch element ----------------
__global__ __launch_bounds__(64) void k_viterbi(const float* __restrict__ ws_c,
                                                const float* __restrict__ trans,
                                                const int* __restrict__ seq_lens,
                                                float* __restrict__ out) {
  __shared__ char bp_s[1024][12];
  int b = blockIdx.x, lane = threadIdx.x;
  int len = seq_lens[b];
  float trow[12];
#pragma unroll
  for (int p = 0; p < 12; ++p) trow[p] = (lane < 12) ? trans[lane * 12 + p] : 0.0f;
  float tb = (lane < 16) ? ws_c[OFF_BTAG + lane] : 0.0f;
  float fv = (lane == 10) ? 0.0f : NEG10K;  // START=10
  const float* ff = ws_c + OFF_FEATS + (size_t)b * 16384;
  const float* fb = ws_c + OFF_FEATS + 1048576 + (size_t)b * 16384;
  for (int t = 0; t < 1024; ++t) {
    float ft = (lane < 16) ? (ff[t * 16 + lane] + fb[t * 16 + lane] + tb) : 0.0f;
    float best = -3.0e38f; int arg = 0;
#pragma unroll
    for (int p = 0; p < 12; ++p) {
      float s = __shfl(fv, p) + trow[p];
      if (s > best) { best = s; arg = p; }
    }
    bool m = t < len;
    if (m) fv = best + ft;
    if (lane < 12) bp_s[t][lane] = (char)(m ? arg : lane);
  }
  float term = (lane < 12) ? fv + trans[132 + lane] : -3.0e38f;  // STOP row = 11
  float bestv = -3.0e38f; int bestp = 0;
#pragma unroll
  for (int p = 0; p < 12; ++p) {
    float v = __shfl(term, p);
    if (v > bestv) { bestv = v; bestp = p; }
  }
  __syncthreads();
  if (lane == 0) {
    out[b] = bestv;
    int tag = bestp;
    float* po = out + 64 + (size_t)b * 1024;
    for (int t = 1023; t >= 0; --t) {
      po[t] = (t < len) ? (float)tag : 0.0f;
      tag = bp_s[t][tag];
    }
  }
}

extern "C" void kernel_launch(void* const* d_in, const int* in_sizes, int n_in,
                              void* d_out, int out_size, void* d_ws, size_t ws_size,
                              hipStream_t stream) {
  (void)in_sizes; (void)n_in; (void)out_size;
  const int*   sentence = (const int*)d_in[0];
  const int*   seq_lens = (const int*)d_in[1];
  const float* emb      = (const float*)d_in[2];
  const float* wih_f    = (const float*)d_in[3];
  const float* whh_f    = (const float*)d_in[4];
  const float* bih_f    = (const float*)d_in[5];
  const float* bhh_f    = (const float*)d_in[6];
  const float* wih_b    = (const float*)d_in[7];
  const float* whh_b    = (const float*)d_in[8];
  const float* bih_b    = (const float*)d_in[9];
  const float* bhh_b    = (const float*)d_in[10];
  const float* wtag     = (const float*)d_in[11];
  const float* btag     = (const float*)d_in[12];
  const float* trans    = (const float*)d_in[13];
  const float* h0p      = (const float*)d_in[14];
  const float* c0p      = (const float*)d_in[15];
  float* ws  = (float*)d_ws;
  float* out = (float*)d_out;
  size_t avail = ws_size / 4;
  if (avail < OFF_FEATS + 2097152) return;

  int chunkT = 0;
  const int opts[4] = {256, 128, 64, 32};
  for (int i = 0; i < 4; ++i)
    if (OFF_G + (size_t)131072 * opts[i] <= avail) { chunkT = opts[i]; break; }

  k_transpose<<<dim3(8, 32, 4), 256, 0, stream>>>(wih_f, wih_b, whh_f, whh_b, ws);
  k_prep_small<<<41, 256, 0, stream>>>(bih_f, bhh_f, bih_b, bhh_b, wtag, btag, ws);
  if (chunkT) {
    int cshift = 31 - __builtin_clz(chunkT);
    int nc = 1024 / chunkT;
    for (int c = 0; c < nc; ++c) {
      int t0 = c * chunkT;
      k_gemm_g<<<dim3(16, chunkT, 2), 256, 0, stream>>>(sentence, emb, ws, ws + OFF_G,
                                                        t0, cshift);
      hipMemsetAsync((char*)d_ws + OFF_CNT * 4, 0, 16 * 256 * 4, stream);
      k_lstm_g<<<64, 512, 0, stream>>>(ws, ws + OFF_G, h0p, c0p, seq_lens, ws,
                                       t0, chunkT, c == 0);
    }
  } else {
    k_lstm_fused<<<64, 256, 0, stream>>>(ws, sentence, emb, h0p, c0p, seq_lens, ws);
  }
  k_viterbi<<<64, 64, 0, stream>>>(ws, trans, seq_lens, out);
}

// Round 8
// 11077.669 us; speedup vs baseline: 1.1903x; 1.0374x over previous
//
#include <hip/hip_runtime.h>
#include <math.h>

#define NEG10K -10000.0f
// K=12 tags, START=10, STOP=11, B=64, T=1024, V=50000, D=256, Hh=256, 4Hh=1024

// ---------------- workspace layout (float offsets) ----------------
// bf16 weight regions measured in float slots (2 bf16 per float).
static const size_t OFF_WTIH_B = 0;                 // [2][256][1024] bf16 Wih^T (shorts 0..524288)
static const size_t OFF_WTHH_B = 262144;            // [2][256][1024] bf16 Whh^T (shorts 524288..1048576)
static const size_t OFF_BIAS   = 524288;            // [2][1024] fp32 bih+bhh
static const size_t OFF_WTAGD  = 526336;            // [2][16][256] fp32 Wtag halves (K pad 16)
static const size_t OFF_BTAG   = 534528;            // [16]
static const size_t OFF_FEATS  = 534544;            // [2][64][1024][16] per-dir partial feats
static const size_t OFF_HC     = 2631696;           // [2][64][256] h carry
static const size_t OFF_CC     = 2664464;           // [2][64][256] c carry
static const size_t OFF_G      = 2697232;           // [2][64][chunkT][1024] fp32 input proj

__device__ __forceinline__ float sigf(float x) { return 1.0f / (1.0f + expf(-x)); }

__device__ __forceinline__ unsigned short f2b(float f) {  // fp32 -> bf16 RNE
  unsigned u = __float_as_uint(f);
  return (unsigned short)((u + 0x7fffu + ((u >> 16) & 1u)) >> 16);
}
__device__ __forceinline__ float4 bf4(uint2 w) {  // 4 packed bf16 -> float4
  float4 r;
  r.x = __uint_as_float(w.x << 16);
  r.y = __uint_as_float(w.x & 0xffff0000u);
  r.z = __uint_as_float(w.y << 16);
  r.w = __uint_as_float(w.y & 0xffff0000u);
  return r;
}

// ---------------- weight transposes: [1024][256] fp32 -> [256][1024] bf16 ----------------
__global__ __launch_bounds__(256) void k_transpose(
    const float* __restrict__ wih_f, const float* __restrict__ wih_b,
    const float* __restrict__ whh_f, const float* __restrict__ whh_b,
    float* __restrict__ ws) {
  __shared__ float tile[32][33];
  int z = blockIdx.z;
  const float* src = (z == 0) ? wih_f : (z == 1) ? wih_b : (z == 2) ? whh_f : whh_b;
  unsigned short* dst = (unsigned short*)ws +
      ((z < 2) ? (size_t)z * 262144 : (524288 + (size_t)(z - 2) * 262144));
  int r0 = blockIdx.y * 32;  // over 1024 rows of src
  int c0 = blockIdx.x * 32;  // over 256 cols of src
  int tid = threadIdx.x;
  int c = tid & 31, rg = tid >> 5;
#pragma unroll
  for (int i = 0; i < 4; ++i) {
    int r = rg * 4 + i;
    tile[r][c] = src[(size_t)(r0 + r) * 256 + c0 + c];
  }
  __syncthreads();
  int r2 = tid & 31, cg = tid >> 5;
#pragma unroll
  for (int i = 0; i < 4; ++i) {
    int ccv = cg * 4 + i;
    dst[(size_t)(c0 + ccv) * 1024 + r0 + r2] = f2b(tile[r2][ccv]);
  }
}

// ---------------- small prep ----------------
__global__ __launch_bounds__(256) void k_prep_small(
    const float* __restrict__ bih_f, const float* __restrict__ bhh_f,
    const float* __restrict__ bih_b, const float* __restrict__ bhh_b,
    const float* __restrict__ wtag, const float* __restrict__ btag,
    float* __restrict__ ws) {
  int i = blockIdx.x * 256 + threadIdx.x;
  if (i < 2048) {
    int d = i >> 10, n = i & 1023;
    ws[OFF_BIAS + i] = d ? (bih_b[n] + bhh_b[n]) : (bih_f[n] + bhh_f[n]);
  } else if (i < 2048 + 8192) {
    int r = i - 2048;
    int d = r >> 12, rem = r & 4095;
    int k = rem >> 8, j = rem & 255;
    ws[OFF_WTAGD + r] = (k < 12) ? wtag[(size_t)k * 512 + d * 256 + j] : 0.0f;
  } else if (i < 2048 + 8192 + 16) {
    int kk = i - 10240;
    ws[OFF_BTAG + kk] = (kk < 12) ? btag[kk] : 0.0f;
  }
}

// ---------------- G chunk = gather(emb, sentence) @ Wih^T(bf16) + bias ----------------
__global__ __launch_bounds__(256) void k_gemm_g(
    const int* __restrict__ sentence, const float* __restrict__ emb,
    const float* __restrict__ ws_c, float* __restrict__ G,
    int t0, int cshift) {
  __shared__ float As[32][64];
  __shared__ float Bs[32][64];
  __shared__ int idx_s[64];
  int d = blockIdx.z;
  int m0 = blockIdx.y * 64, n0 = blockIdx.x * 64;
  int tid = threadIdx.x;
  int cmask = (1 << cshift) - 1;
  const unsigned short* Wt = (const unsigned short*)ws_c + (size_t)d * 262144;
  if (tid < 64) {
    int m = m0 + tid;
    int b = m >> cshift, tt = m & cmask;
    int t = d ? (1023 - t0 - tt) : (t0 + tt);
    idx_s[tid] = sentence[(size_t)b * 1024 + t];
  }
  __syncthreads();
  float acc[4][4] = {};
  int tm = tid >> 4, tn = tid & 15;
  int am = tid & 63, ak = (tid >> 6) * 8;
  int bn = (tid & 15) * 4, bk = tid >> 4;
  for (int k0 = 0; k0 < 256; k0 += 32) {
    const float* ar = emb + (size_t)idx_s[am] * 256 + k0 + ak;
    float4 a0 = *(const float4*)ar;
    float4 a1 = *(const float4*)(ar + 4);
    float4 b0 = bf4(*(const uint2*)(Wt + (size_t)(k0 + bk) * 1024 + n0 + bn));
    float4 b1 = bf4(*(const uint2*)(Wt + (size_t)(k0 + bk + 16) * 1024 + n0 + bn));
    As[ak + 0][am] = a0.x; As[ak + 1][am] = a0.y; As[ak + 2][am] = a0.z; As[ak + 3][am] = a0.w;
    As[ak + 4][am] = a1.x; As[ak + 5][am] = a1.y; As[ak + 6][am] = a1.z; As[ak + 7][am] = a1.w;
    *(float4*)&Bs[bk][bn] = b0;
    *(float4*)&Bs[bk + 16][bn] = b1;
    __syncthreads();
#pragma unroll
    for (int kk = 0; kk < 32; ++kk) {
      float4 av = *(const float4*)&As[kk][tm * 4];
      float4 bv = *(const float4*)&Bs[kk][tn * 4];
      float avf[4] = {av.x, av.y, av.z, av.w};
      float bvf[4] = {bv.x, bv.y, bv.z, bv.w};
#pragma unroll
      for (int i = 0; i < 4; ++i)
#pragma unroll
        for (int j = 0; j < 4; ++j) acc[i][j] = fmaf(avf[i], bvf[j], acc[i][j]);
    }
    __syncthreads();
  }
  float4 bias = *(const float4*)(ws_c + OFF_BIAS + (size_t)d * 1024 + n0 + tn * 4);
#pragma unroll
  for (int i = 0; i < 4; ++i) {
    int m = m0 + tm * 4 + i;
    int b = m >> cshift, tt = m & cmask;
    float* gp = G + (((size_t)d * 64 + b) * (size_t)(cmask + 1) + tt) * 1024 + n0 + tn * 4;
    float4 v;
    v.x = acc[i][0] + bias.x; v.y = acc[i][1] + bias.y;
    v.z = acc[i][2] + bias.z; v.w = acc[i][3] + bias.w;
    *(float4*)gp = v;
  }
}

// ---------------- recurrent LSTM (bf16 Whh) + fused tag-head ----------------
// 64 WGs = (32 batch-pairs) x (2 dirs); 512 threads = 8 waves.
// Waves 0-3: k in [0,128); waves 4-7: k in [128,256). Thread owns 4 gate cols
// (uint2 bf16 weight loads, in-register unpack). z halves summed in phase B.
#define FMA4(A, W, S) { A.x = fmaf(W.x, S, A.x); A.y = fmaf(W.y, S, A.y); \
                        A.z = fmaf(W.z, S, A.z); A.w = fmaf(W.w, S, A.w); }
__global__ __launch_bounds__(512, 2) void k_lstm_g(
    const float* __restrict__ ws_c, const float* __restrict__ G,
    const float* __restrict__ h0p, const float* __restrict__ c0p,
    const int* __restrict__ seq_lens, float* __restrict__ ws_mut,
    int t0, int chunkT, int first) {
  int d = blockIdx.x & 1;
  int pr = blockIdx.x >> 1;
  int b0 = pr * 2;
  const unsigned short* Whh = (const unsigned short*)ws_c + 524288 + (size_t)d * 262144;

  __shared__ float h_s[2][256];
  __shared__ float g_s[2][2][1024];   // [buf][batch][gatecol]
  __shared__ float z_s[2][2][1024];   // [khalf][batch][gatecol]
  __shared__ float wt_s[16][260];
  __shared__ float pfp_s[2][16][16];

  int tid = threadIdx.x;
  int bb = tid >> 8, u = tid & 255;   // bb doubles as k-half for phase A
  int c4 = u * 4;
  int len0 = seq_lens[b0], len1 = seq_lens[b0 + 1];
  int mylen = bb ? len1 : len0;

  for (int i = tid; i < 4096; i += 512)
    wt_s[i >> 8][i & 255] = ws_c[OFF_WTAGD + (size_t)d * 4096 + i];

  size_t hci = ((size_t)d * 64 + b0 + bb) * 256 + u;
  float cc;
  if (first) { h_s[bb][u] = h0p[hci]; cc = c0p[hci]; }
  else       { h_s[bb][u] = ws_c[OFF_HC + hci]; cc = ws_c[OFF_CC + hci]; }

  const float* Gb = G + (((size_t)d * 64 + b0 + bb) * (size_t)chunkT) * 1024;
  *(float4*)&g_s[0][bb][c4] = *(const float4*)(Gb + c4);  // step-0 inputs
  __syncthreads();

  float* featsD = ws_mut + OFF_FEATS + (size_t)d * 1048576;

  for (int s = 0; s < chunkT; ++s) {
    int sg = t0 + s;
    int t = d ? (1023 - sg) : sg;
    int cur = s & 1, nxt = cur ^ 1;
    // prefetch next step's G row (stashed to LDS in phase B)
    int srow = (s + 1 < chunkT) ? (s + 1) : s;
    float4 gpf = *(const float4*)(Gb + (size_t)srow * 1024 + c4);
    // ---- phase A: half-k partial z for 4 cols x 2 batches, bf16 weights ----
    float4 acc0 = {0, 0, 0, 0}, acc1 = {0, 0, 0, 0};
#pragma unroll 4
    for (int j = 0; j < 32; ++j) {
      int k = bb * 128 + j * 4;
      float4 hv0 = *(const float4*)&h_s[0][k];
      float4 hv1 = *(const float4*)&h_s[1][k];
      const unsigned short* wp = Whh + (size_t)k * 1024 + c4;
      float4 w0 = bf4(*(const uint2*)(wp));
      float4 w1 = bf4(*(const uint2*)(wp + 1024));
      float4 w2 = bf4(*(const uint2*)(wp + 2048));
      float4 w3 = bf4(*(const uint2*)(wp + 3072));
      FMA4(acc0, w0, hv0.x); FMA4(acc0, w1, hv0.y); FMA4(acc0, w2, hv0.z); FMA4(acc0, w3, hv0.w);
      FMA4(acc1, w0, hv1.x); FMA4(acc1, w1, hv1.y); FMA4(acc1, w2, hv1.z); FMA4(acc1, w3, hv1.w);
    }
    *(float4*)&z_s[bb][0][c4] = acc0;
    *(float4*)&z_s[bb][1][c4] = acc1;
    __syncthreads();  // S1
    // ---- phase B: gates for (batch bb, unit u); G already includes bias ----
    {
      float zi = z_s[0][bb][u]       + z_s[1][bb][u]       + g_s[cur][bb][u];
      float zf = z_s[0][bb][u + 256] + z_s[1][bb][u + 256] + g_s[cur][bb][u + 256];
      float zg = z_s[0][bb][u + 512] + z_s[1][bb][u + 512] + g_s[cur][bb][u + 512];
      float zo = z_s[0][bb][u + 768] + z_s[1][bb][u + 768] + g_s[cur][bb][u + 768];
      float cn = sigf(zf) * cc + sigf(zi) * tanhf(zg);
      float hn = sigf(zo) * tanhf(cn);
      bool m = t < mylen;
      cc = m ? cn : cc;
      h_s[bb][u] = m ? hn : h_s[bb][u];
    }
    *(float4*)&g_s[nxt][bb][c4] = gpf;
    __syncthreads();  // S2
    // ---- phase C: partial tag-head ----
    {
      int ks = u >> 4, jg = u & 15;
      float p = 0.0f;
#pragma unroll
      for (int i = 0; i < 16; ++i)
        p = fmaf(h_s[bb][jg + 16 * i], wt_s[ks][jg + 16 * i], p);
      pfp_s[bb][ks][jg] = p;
    }
    __syncthreads();  // S3
    if (tid < 32) {
      int b = tid >> 4, k = tid & 15;
      float sum = 0.0f;
#pragma unroll
      for (int i = 0; i < 16; ++i) sum += pfp_s[b][k][i];
      featsD[(size_t)(b0 + b) * 16384 + (size_t)t * 16 + k] = sum;
    }
  }
  ws_mut[OFF_HC + hci] = h_s[bb][u];
  ws_mut[OFF_CC + hci] = cc;
}

// ---------------- fallback fused LSTM (bf16 weights) ----------------
__global__ __launch_bounds__(256) void k_lstm_fused(
    const float* __restrict__ ws_c, const int* __restrict__ sentence,
    const float* __restrict__ emb, const float* __restrict__ h0p,
    const float* __restrict__ c0p, const int* __restrict__ seq_lens,
    float* __restrict__ ws_mut) {
  int d = blockIdx.x & 1;
  int pr = blockIdx.x >> 1;
  int b0 = pr * 2, b1 = b0 + 1;
  const unsigned short* Wih = (const unsigned short*)ws_c + (size_t)d * 262144;
  const unsigned short* Whh = (const unsigned short*)ws_c + 524288 + (size_t)d * 262144;
  __shared__ float h_s[2][256];
  __shared__ float x_s[2][2][256];
  __shared__ float z_s[2][1024];
  __shared__ int   sent_s[2][1024];
  __shared__ float wt_s[16][260];
  __shared__ float pfp_s[2][16][8];
  int tid = threadIdx.x;
  int len0 = seq_lens[b0], len1 = seq_lens[b1];
  for (int i = tid; i < 2048; i += 256)
    sent_s[i >> 10][i & 1023] = sentence[(size_t)(b0 + (i >> 10)) * 1024 + (i & 1023)];
  for (int i = tid; i < 4096; i += 256)
    wt_s[i >> 8][i & 255] = ws_c[OFF_WTAGD + (size_t)d * 4096 + i];
  h_s[0][tid] = h0p[((size_t)d * 64 + b0) * 256 + tid];
  h_s[1][tid] = h0p[((size_t)d * 64 + b1) * 256 + tid];
  float cc0 = c0p[((size_t)d * 64 + b0) * 256 + tid];
  float cc1 = c0p[((size_t)d * 64 + b1) * 256 + tid];
  int c4 = tid * 4;
  float4 bias_v = *(const float4*)(ws_c + OFF_BIAS + (size_t)d * 1024 + c4);
  __syncthreads();
  int t0 = d ? 1023 : 0;
  if (tid < 128) {
    int bb = tid >> 6, l = tid & 63;
    int row = sent_s[bb][t0];
    *(float4*)&x_s[0][bb][l * 4] = *(const float4*)(emb + (size_t)row * 256 + l * 4);
  }
  __syncthreads();
  float* featsD = ws_mut + OFF_FEATS + (size_t)d * 1048576;
  for (int s = 0; s < 1024; ++s) {
    int t = d ? (1023 - s) : s;
    int cur = s & 1, nxt = cur ^ 1;
    float4 pf = {0, 0, 0, 0};
    if (tid < 128) {
      int sn = (s < 1023) ? (s + 1) : 1023;
      int tn = d ? (1023 - sn) : sn;
      int bb = tid >> 6, l = tid & 63;
      pf = *(const float4*)(emb + (size_t)sent_s[bb][tn] * 256 + l * 4);
    }
    float4 a0 = bias_v, a1 = bias_v;
#pragma unroll 4
    for (int k = 0; k < 256; k += 4) {
      float4 xv0 = *(const float4*)&x_s[cur][0][k];
      float4 xv1 = *(const float4*)&x_s[cur][1][k];
      float4 hv0 = *(const float4*)&h_s[0][k];
      float4 hv1 = *(const float4*)&h_s[1][k];
      const unsigned short* wi = Wih + (size_t)k * 1024 + c4;
      const unsigned short* wh = Whh + (size_t)k * 1024 + c4;
      float4 wi0 = bf4(*(const uint2*)(wi));
      float4 wi1 = bf4(*(const uint2*)(wi + 1024));
      float4 wi2 = bf4(*(const uint2*)(wi + 2048));
      float4 wi3 = bf4(*(const uint2*)(wi + 3072));
      float4 wh0 = bf4(*(const uint2*)(wh));
      float4 wh1 = bf4(*(const uint2*)(wh + 1024));
      float4 wh2 = bf4(*(const uint2*)(wh + 2048));
      float4 wh3 = bf4(*(const uint2*)(wh + 3072));
      FMA4(a0, wi0, xv0.x); FMA4(a0, wi1, xv0.y); FMA4(a0, wi2, xv0.z); FMA4(a0, wi3, xv0.w);
      FMA4(a0, wh0, hv0.x); FMA4(a0, wh1, hv0.y); FMA4(a0, wh2, hv0.z); FMA4(a0, wh3, hv0.w);
      FMA4(a1, wi0, xv1.x); FMA4(a1, wi1, xv1.y); FMA4(a1, wi2, xv1.z); FMA4(a1, wi3, xv1.w);
      FMA4(a1, wh0, hv1.x); FMA4(a1, wh1, hv1.y); FMA4(a1, wh2, hv1.z); FMA4(a1, wh3, hv1.w);
    }
    *(float4*)&z_s[0][c4] = a0;
    *(float4*)&z_s[1][c4] = a1;
    __syncthreads();
    {
      float iv = z_s[0][tid], fv = z_s[0][tid + 256];
      float gv = z_s[0][tid + 512], ov = z_s[0][tid + 768];
      float cn = sigf(fv) * cc0 + sigf(iv) * tanhf(gv);
      float hn = sigf(ov) * tanhf(cn);
      bool m = t < len0;
      cc0 = m ? cn : cc0;
      h_s[0][tid] = m ? hn : h_s[0][tid];
    }
    {
      float iv = z_s[1][tid], fv = z_s[1][tid + 256];
      float gv = z_s[1][tid + 512], ov = z_s[1][tid + 768];
      float cn = sigf(fv) * cc1 + sigf(iv) * tanhf(gv);
      float hn = sigf(ov) * tanhf(cn);
      bool m = t < len1;
      cc1 = m ? cn : cc1;
      h_s[1][tid] = m ? hn : h_s[1][tid];
    }
    if (tid < 128) {
      int bb = tid >> 6, l = tid & 63;
      *(float4*)&x_s[nxt][bb][l * 4] = pf;
    }
    __syncthreads();
    {
      int b2 = tid >> 7, r = tid & 127;
      int ks = r >> 3, jg = r & 7;
      const float* hv = &h_s[b2][jg * 32];
      const float* wv = &wt_s[ks][jg * 32];
      float p = 0.0f;
#pragma unroll
      for (int i = 0; i < 32; ++i) p = fmaf(hv[i], wv[i], p);
      pfp_s[b2][ks][jg] = p;
    }
    __syncthreads();
    if (tid < 32) {
      int b = tid >> 4, k = tid & 15;
      float sum = 0.0f;
#pragma unroll
      for (int i = 0; i < 8; ++i) sum += pfp_s[b][k][i];
      featsD[(size_t)(b0 + b) * 16384 + (size_t)t * 16 + k] = sum;
    }
  }
}

// ---------------- Viterbi + backtrace, one wave per batch element ----------------
__global__ __launch_bounds__(64) void k_viterbi(const float* __restrict__ ws_c,
                                                const float* __restrict__ trans,
                                                const int* __restrict__ seq_lens,
                                                float* __restrict__ out) {
  __shared__ char bp_s[1024][12];
  int b = blockIdx.x, lane = threadIdx.x;
  int len = seq_lens[b];
  float trow[12];
#pragma unroll
  for (int p = 0; p < 12; ++p) trow[p] = (lane < 12) ? trans[lane * 12 + p] : 0.0f;
  float tb = (lane < 16) ? ws_c[OFF_BTAG + lane] : 0.0f;
  float fv = (lane == 10) ? 0.0f : NEG10K;  // START=10
  const float* ff = ws_c + OFF_FEATS + (size_t)b * 16384;
  const float* fb = ws_c + OFF_FEATS + 1048576 + (size_t)b * 16384;
  for (int t = 0; t < 1024; ++t) {
    float ft = (lane < 16) ? (ff[t * 16 + lane] + fb[t * 16 + lane] + tb) : 0.0f;
    float best = -3.0e38f; int arg = 0;
#pragma unroll
    for (int p = 0; p < 12; ++p) {
      float s = __shfl(fv, p) + trow[p];
      if (s > best) { best = s; arg = p; }
    }
    bool m = t < len;
    if (m) fv = best + ft;
    if (lane < 12) bp_s[t][lane] = (char)(m ? arg : lane);
  }
  float term = (lane < 12) ? fv + trans[132 + lane] : -3.0e38f;  // STOP row = 11
  float bestv = -3.0e38f; int bestp = 0;
#pragma unroll
  for (int p = 0; p < 12; ++p) {
    float v = __shfl(term, p);
    if (v > bestv) { bestv = v; bestp = p; }
  }
  __syncthreads();
  if (lane == 0) {
    out[b] = bestv;
    int tag = bestp;
    float* po = out + 64 + (size_t)b * 1024;
    for (int t = 1023; t >= 0; --t) {
      po[t] = (t < len) ? (float)tag : 0.0f;
      tag = bp_s[t][tag];
    }
  }
}

extern "C" void kernel_launch(void* const* d_in, const int* in_sizes, int n_in,
                              void* d_out, int out_size, void* d_ws, size_t ws_size,
                              hipStream_t stream) {
  (void)in_sizes; (void)n_in; (void)out_size;
  const int*   sentence = (const int*)d_in[0];
  const int*   seq_lens = (const int*)d_in[1];
  const float* emb      = (const float*)d_in[2];
  const float* wih_f    = (const float*)d_in[3];
  const float* whh_f    = (const float*)d_in[4];
  const float* bih_f    = (const float*)d_in[5];
  const float* bhh_f    = (const float*)d_in[6];
  const float* wih_b    = (const float*)d_in[7];
  const float* whh_b    = (const float*)d_in[8];
  const float* bih_b    = (const float*)d_in[9];
  const float* bhh_b    = (const float*)d_in[10];
  const float* wtag     = (const float*)d_in[11];
  const float* btag     = (const float*)d_in[12];
  const float* trans    = (const float*)d_in[13];
  const float* h0p      = (const float*)d_in[14];
  const float* c0p      = (const float*)d_in[15];
  float* ws  = (float*)d_ws;
  float* out = (float*)d_out;
  size_t avail = ws_size / 4;
  if (avail < OFF_G) return;

  int chunkT = 0;
  const int opts[4] = {256, 128, 64, 32};
  for (int i = 0; i < 4; ++i)
    if (OFF_G + (size_t)131072 * opts[i] <= avail) { chunkT = opts[i]; break; }

  k_transpose<<<dim3(8, 32, 4), 256, 0, stream>>>(wih_f, wih_b, whh_f, whh_b, ws);
  k_prep_small<<<41, 256, 0, stream>>>(bih_f, bhh_f, bih_b, bhh_b, wtag, btag, ws);
  if (chunkT) {
    int cshift = 31 - __builtin_clz(chunkT);
    int nc = 1024 / chunkT;
    for (int c = 0; c < nc; ++c) {
      int t0 = c * chunkT;
      k_gemm_g<<<dim3(16, chunkT, 2), 256, 0, stream>>>(sentence, emb, ws, ws + OFF_G,
                                                        t0, cshift);
      k_lstm_g<<<64, 512, 0, stream>>>(ws, ws + OFF_G, h0p, c0p, seq_lens, ws,
                                       t0, chunkT, c == 0);
    }
  } else {
    k_lstm_fused<<<64, 256, 0, stream>>>(ws, sentence, emb, h0p, c0p, seq_lens, ws);
  }
  k_viterbi<<<64, 64, 0, stream>>>(ws, trans, seq_lens, out);
}